// Round 2
// baseline (7000.479 us; speedup 1.0000x reference)
//
#include <hip/hip_runtime.h>
#include <hip/hip_bf16.h>
#include <stdint.h>

typedef __attribute__((ext_vector_type(4))) float f32x4;
typedef __attribute__((ext_vector_type(8))) short short8;

#define B_   32
#define T_   1024
#define E_   256
#define HD_  256
#define K_   48
#define NEG_ (-10000.0f)
#define NWGD 16   // workgroups per direction

__device__ __forceinline__ short f2bf(float f){
  union { float f; unsigned u; } v; v.f = f;
  unsigned r = v.u + 0x7fffu + ((v.u >> 16) & 1u);   // RNE
  return (short)(r >> 16);
}
__device__ __forceinline__ short8 pack8v(float4 a, float4 b){
  short8 r;
  r[0]=f2bf(a.x); r[1]=f2bf(a.y); r[2]=f2bf(a.z); r[3]=f2bf(a.w);
  r[4]=f2bf(b.x); r[5]=f2bf(b.y); r[6]=f2bf(b.z); r[7]=f2bf(b.w);
  return r;
}
__device__ __forceinline__ float sigm(float x){ return 1.0f/(1.0f + __expf(-x)); }
__device__ __forceinline__ float tanh_f(float x){ return 1.0f - 2.0f/(1.0f + __expf(2.0f*x)); }

// ---------------------------------------------------------------------------
// LSTM: 32 blocks = 16 per direction. Block (dir,w) owns hidden units
// [16w,16w+16) -> 64 gate rows. Wih slice in LDS (bf16, swizzled), Whh slice
// in registers. Per step: barrier over the direction's 16 wgs, h exchanged
// via global ping-pong buffer (bf16).
// ---------------------------------------------------------------------------
__global__ __launch_bounds__(128, 1)
void lstm_k(const int* __restrict__ sent, const float* __restrict__ emb,
            const float* __restrict__ Wih_f, const float* __restrict__ Whh_f,
            const float* __restrict__ bih_f, const float* __restrict__ bhh_f,
            const float* __restrict__ Wih_b, const float* __restrict__ Whh_b,
            const float* __restrict__ bih_b, const float* __restrict__ bhh_b,
            unsigned short* __restrict__ h_ex, unsigned* __restrict__ cnt,
            unsigned short* __restrict__ h_all)
{
  __shared__ __align__(16) unsigned short WihLds[64*256];   // 32 KB

  const int bid  = blockIdx.x;
  const int dir  = bid & 1;
  const int w    = bid >> 1;          // 0..15
  const int tid  = threadIdx.x;
  const int wave = tid >> 6;          // Mtile (batch half)
  const int lane = tid & 63;
  const int l15  = lane & 15;
  const int lq   = lane >> 4;

  const float* Wih = dir ? Wih_b : Wih_f;
  const float* Whh = dir ? Whh_b : Whh_f;
  const float* bih = dir ? bih_b : bih_f;
  const float* bhh = dir ? bhh_b : bhh_f;

  // stage Wih slice -> LDS bf16, XOR-swizzled (rows stride 512B would be
  // 16-way bank conflict on ds_read_b128 otherwise)
  for (int idx = tid; idx < 64*256; idx += 128){
    int n = idx >> 8, kus = idx & 255;
    int j = (n >> 4)*256 + w*16 + (n & 15);    // gate*256 + unit
    WihLds[n*256 + (kus ^ ((n & 7) << 3))] = (unsigned short)f2bf(Wih[j*256 + kus]);
  }

  // Whh fragments in registers: B[k][col] = Whh[row=g*256+16w+l15][k]
  short8 wh[4][8];
  #pragma unroll
  for (int g = 0; g < 4; ++g){
    int j = g*256 + w*16 + l15;
    #pragma unroll
    for (int kc = 0; kc < 8; ++kc){
      const float* p = Whh + j*256 + kc*32 + lq*8;
      float4 a = *(const float4*)p, b = *(const float4*)(p + 4);
      wh[g][kc] = pack8v(a, b);
    }
  }
  float bias[4];
  #pragma unroll
  for (int g = 0; g < 4; ++g){
    int j = g*256 + w*16 + l15;
    bias[g] = bih[j] + bhh[j];
  }

  float c[4] = {0.f, 0.f, 0.f, 0.f};
  unsigned* cnt_d = cnt + dir*T_;
  const int arow = wave*16 + l15;                 // A-fragment row (batch)
  int tok = sent[arow*T_ + (dir ? (T_-1) : 0)];   // prefetched token

  __syncthreads();

  for (int s = 0; s < T_; ++s){
    const int t_idx = dir ? (T_-1 - s) : s;

    // ---- issue x loads early (independent of the barrier) ----
    const float* xr = emb + (long)tok*E_ + lq*8;
    float4 xa0[8], xa1[8];
    #pragma unroll
    for (int kc = 0; kc < 8; ++kc){
      xa0[kc] = *(const float4*)(xr + kc*32);
      xa1[kc] = *(const float4*)(xr + kc*32 + 4);
    }
    if (s + 1 < T_) tok = sent[arow*T_ + (dir ? (T_-2 - s) : (s+1))];

    // ---- wait for h(s) from all 16 wgs of this direction ----
    if (s > 0){
      if (tid == 0){
        while (__hip_atomic_load(&cnt_d[s-1], __ATOMIC_RELAXED,
                                 __HIP_MEMORY_SCOPE_AGENT) < NWGD) { }
      }
      __syncthreads();
      __builtin_amdgcn_fence(__ATOMIC_ACQUIRE, "agent");
    }

    // ---- h fragments from ping-pong buffer buf[s&1] ----
    const unsigned short* hbp = h_ex + (((s & 1)*2 + dir)*B_ + arow)*HD_ + lq*8;
    short8 ha[8];
    #pragma unroll
    for (int kc = 0; kc < 8; ++kc) ha[kc] = *(const short8*)(hbp + kc*32);

    short8 xa[8];
    #pragma unroll
    for (int kc = 0; kc < 8; ++kc) xa[kc] = pack8v(xa0[kc], xa1[kc]);

    // ---- gates = bias + x@Wih^T + h@Whh^T (bf16 MFMA, f32 acc) ----
    f32x4 acc[4];
    #pragma unroll
    for (int g = 0; g < 4; ++g) acc[g] = (f32x4){bias[g], bias[g], bias[g], bias[g]};
    #pragma unroll
    for (int kc = 0; kc < 8; ++kc){
      #pragma unroll
      for (int g = 0; g < 4; ++g){
        int n = g*16 + l15;
        short8 bw = *(const short8*)&WihLds[n*256 + ((kc*32 + lq*8) ^ ((n & 7) << 3))];
        acc[g] = __builtin_amdgcn_mfma_f32_16x16x32_bf16(xa[kc], bw, acc[g], 0, 0, 0);
      }
    }
    #pragma unroll
    for (int kc = 0; kc < 8; ++kc){
      #pragma unroll
      for (int g = 0; g < 4; ++g)
        acc[g] = __builtin_amdgcn_mfma_f32_16x16x32_bf16(ha[kc], wh[g][kc], acc[g], 0, 0, 0);
    }

    // ---- lane-local cell update: lane holds (4 batches, 1 unit) ----
    const int u = w*16 + l15;
    unsigned short* hw = h_ex + ((((s+1) & 1)*2 + dir)*B_)*HD_;
    unsigned short* hs = h_all + ((dir*T_ + t_idx)*B_)*HD_;
    #pragma unroll
    for (int r = 0; r < 4; ++r){
      float iv = sigm(acc[0][r]);
      float fv = sigm(acc[1][r]);
      float gv = tanh_f(acc[2][r]);
      float ov = sigm(acc[3][r]);
      c[r] = fv*c[r] + iv*gv;
      float hv = ov*tanh_f(c[r]);
      int m = wave*16 + lq*4 + r;
      unsigned short hb16 = (unsigned short)f2bf(hv);
      hw[m*HD_ + u] = hb16;
      hs[m*HD_ + u] = hb16;
    }

    __builtin_amdgcn_fence(__ATOMIC_RELEASE, "agent");
    __syncthreads();
    if (tid == 0)
      __hip_atomic_fetch_add(&cnt_d[s], 1u, __ATOMIC_RELEASE, __HIP_MEMORY_SCOPE_AGENT);
  }
}

// ---------------------------------------------------------------------------
// feats[b][t][k] = b_out[k] + [hf|hb] @ W_out^T   (K=512, N=48, M=B*T)
// ---------------------------------------------------------------------------
__global__ __launch_bounds__(128)
void feats_k(const unsigned short* __restrict__ h_all,
             const float* __restrict__ W_out, const float* __restrict__ b_out,
             float* __restrict__ feats)
{
  __shared__ __align__(16) unsigned short Wlds[48*512];   // 48 KB

  const int t0   = blockIdx.x * 4;
  const int tid  = threadIdx.x;
  const int wv   = tid >> 6;
  const int lane = tid & 63;
  const int l15  = lane & 15;
  const int lq   = lane >> 4;

  for (int idx = tid; idx < 48*512; idx += 128){
    int n = idx >> 9, kus = idx & 511;
    Wlds[n*512 + (kus ^ ((n & 7) << 3))] = (unsigned short)f2bf(W_out[n*512 + kus]);
  }
  float bo[3];
  #pragma unroll
  for (int nt = 0; nt < 3; ++nt) bo[nt] = b_out[nt*16 + l15];
  __syncthreads();

  #pragma unroll
  for (int mi = 0; mi < 4; ++mi){
    int mt = wv*4 + mi;
    int m  = mt*16 + l15;          // A row
    int b  = m & 31, tl = m >> 5;
    const unsigned short* hf = h_all + (((t0 + tl))*B_ + b)*HD_ + lq*8;
    const unsigned short* hb = h_all + ((T_ + t0 + tl)*B_ + b)*HD_ + lq*8;
    short8 af[16];
    #pragma unroll
    for (int kc = 0; kc < 8; ++kc) af[kc]     = *(const short8*)(hf + kc*32);
    #pragma unroll
    for (int kc = 0; kc < 8; ++kc) af[kc + 8] = *(const short8*)(hb + kc*32);

    f32x4 acc[3];
    #pragma unroll
    for (int nt = 0; nt < 3; ++nt) acc[nt] = (f32x4){bo[nt], bo[nt], bo[nt], bo[nt]};
    #pragma unroll
    for (int kc = 0; kc < 16; ++kc){
      #pragma unroll
      for (int nt = 0; nt < 3; ++nt){
        int n = nt*16 + l15;
        short8 bw = *(const short8*)&Wlds[n*512 + ((kc*32 + lq*8) ^ ((n & 7) << 3))];
        acc[nt] = __builtin_amdgcn_mfma_f32_16x16x32_bf16(af[kc], bw, acc[nt], 0, 0, 0);
      }
    }
    #pragma unroll
    for (int nt = 0; nt < 3; ++nt){
      #pragma unroll
      for (int r = 0; r < 4; ++r){
        int mm = mt*16 + lq*4 + r;
        int bb = mm & 31, tt = t0 + (mm >> 5);
        feats[(bb*T_ + tt)*K_ + nt*16 + l15] = acc[nt][r];
      }
    }
  }
}

// ---------------------------------------------------------------------------
// Viterbi: one block (one wave) per batch element. DP uses trans[to][from]
// (as the reference does), score recompute uses trans[from][to] + the
// reference's quirky t=0 term (feats[b, T-1, tags[0]]).
// ---------------------------------------------------------------------------
__global__ __launch_bounds__(64)
void viterbi_k(const float* __restrict__ feats, const float* __restrict__ trans,
               float* __restrict__ out)
{
  __shared__ float trans_s[K_*K_];
  __shared__ unsigned char bp[T_][K_];
  __shared__ unsigned char tags[T_];
  __shared__ float red[64];

  const int b = blockIdx.x, lane = threadIdx.x;
  for (int i = lane; i < K_*K_; i += 64) trans_s[i] = trans[i];

  float trow[K_];
  if (lane < K_){
    #pragma unroll
    for (int j = 0; j < K_; ++j) trow[j] = trans[lane*K_ + j];
  }
  float fv = (lane == K_-1) ? 0.0f : NEG_;
  const float* fb = feats + (long)b*T_*K_;
  __syncthreads();

  for (int t = 0; t < T_; ++t){
    float ft = (lane < K_) ? fb[t*K_ + lane] : 0.0f;
    float m = __shfl(fv, 0) + trow[0];
    int idx = 0;
    #pragma unroll
    for (int j = 1; j < K_; ++j){
      float v = __shfl(fv, j) + trow[j];
      if (v > m){ m = v; idx = j; }         // strict > == first-index argmax
    }
    if (lane < K_){
      fv = m + ft;
      bp[t][lane] = (unsigned char)idx;
    }
  }
  __syncthreads();

  red[lane] = fv;
  __syncthreads();
  int last = 0;
  {
    float bm = red[0];
    for (int k = 1; k < K_; ++k){ float v = red[k]; if (v > bm){ bm = v; last = k; } }
  }
  if (lane == 0){
    int tg = last;
    tags[T_-1] = (unsigned char)tg;
    for (int t = T_-1; t >= 1; --t){
      tg = bp[t][tg];
      tags[t-1] = (unsigned char)tg;
    }
  }
  __syncthreads();

  float sc = 0.0f;
  for (int t = 1 + lane; t < T_; t += 64){
    int tt = tags[t], tp = tags[t-1];
    sc += fb[t*K_ + tt] + trans_s[tp*K_ + tt];
  }
  if (lane == 0) sc += fb[(T_-1)*K_ + tags[0]];
  red[lane] = sc;
  __syncthreads();
  if (lane == 0){
    float tot = 0.f;
    for (int i = 0; i < 64; ++i) tot += red[i];
    out[b] = tot;
  }
  for (int t = lane; t < T_; t += 64)
    out[B_ + b*T_ + t] = (float)tags[t];
}

// ---------------------------------------------------------------------------
extern "C" void kernel_launch(void* const* d_in, const int* in_sizes, int n_in,
                              void* d_out, int out_size, void* d_ws, size_t ws_size,
                              hipStream_t stream)
{
  const int*   sent  = (const int*)  d_in[0];
  const float* emb   = (const float*)d_in[1];
  const float* Wih_f = (const float*)d_in[2];
  const float* Whh_f = (const float*)d_in[3];
  const float* bih_f = (const float*)d_in[4];
  const float* bhh_f = (const float*)d_in[5];
  const float* Wih_b = (const float*)d_in[6];
  const float* Whh_b = (const float*)d_in[7];
  const float* bih_b = (const float*)d_in[8];
  const float* bhh_b = (const float*)d_in[9];
  const float* W_out = (const float*)d_in[10];
  const float* b_out = (const float*)d_in[11];
  const float* trans = (const float*)d_in[12];

  char* ws = (char*)d_ws;
  // [0,65536)          h_ex  bf16 [2 buf][2 dir][32][256]
  // [65536,73728)      cnt   u32  [2 dir][1024]
  // [73728,+32MB)      h_all bf16 [2 dir][1024][32][256]
  // [..., +6MB)        feats f32  [32][1024][48]
  unsigned short* h_ex  = (unsigned short*)ws;
  unsigned*       cnt   = (unsigned*)(ws + 65536);
  unsigned short* h_all = (unsigned short*)(ws + 73728);
  float*          feats = (float*)(ws + 73728 + 33554432);

  hipMemsetAsync(ws, 0, 73728, stream);   // zero h-state + barrier counters

  hipLaunchKernelGGL(lstm_k, dim3(32), dim3(128), 0, stream,
                     sent, emb, Wih_f, Whh_f, bih_f, bhh_f,
                     Wih_b, Whh_b, bih_b, bhh_b, h_ex, cnt, h_all);
  hipLaunchKernelGGL(feats_k, dim3(256), dim3(128), 0, stream,
                     h_all, W_out, b_out, feats);
  hipLaunchKernelGGL(viterbi_k, dim3(32), dim3(64), 0, stream,
                     feats, trans, (float*)d_out);
}

// Round 3
// 5794.415 us; speedup vs baseline: 1.2081x; 1.2081x over previous
//
#include <hip/hip_runtime.h>
#include <hip/hip_bf16.h>
#include <stdint.h>

typedef __attribute__((ext_vector_type(4))) float f32x4;
typedef __attribute__((ext_vector_type(8))) short short8;
typedef unsigned long long u64;

#define B_   32
#define T_   1024
#define E_   256
#define HD_  256
#define K_   48
#define NEG_ (-10000.0f)
#define NWGD 16   // workgroups per direction

__device__ __forceinline__ short f2bf(float f){
  union { float f; unsigned u; } v; v.f = f;
  unsigned r = v.u + 0x7fffu + ((v.u >> 16) & 1u);   // RNE
  return (short)(r >> 16);
}
__device__ __forceinline__ short8 pack8v(float4 a, float4 b){
  short8 r;
  r[0]=f2bf(a.x); r[1]=f2bf(a.y); r[2]=f2bf(a.z); r[3]=f2bf(a.w);
  r[4]=f2bf(b.x); r[5]=f2bf(b.y); r[6]=f2bf(b.z); r[7]=f2bf(b.w);
  return r;
}
__device__ __forceinline__ float sigm(float x){ return 1.0f/(1.0f + __expf(-x)); }
__device__ __forceinline__ float tanh_f(float x){ return 1.0f - 2.0f/(1.0f + __expf(2.0f*x)); }

// ---------------------------------------------------------------------------
// LSTM: 32 blocks = 16 per direction. Block (dir,w) owns hidden units
// [16w,16w+16) -> 64 gate rows. Wih slice in LDS (bf16, swizzled), Whh slice
// in registers. Per step: hand-rolled agent-scope sync (NO C++ fences -> no
// per-step L2 invalidate/writeback). h exchanged via sc-flagged 8B atomics;
// h writes coalesced through a 1KB LDS transpose tile.
// ---------------------------------------------------------------------------
__global__ __launch_bounds__(128, 1)
void lstm_k(const int* __restrict__ sent, const float* __restrict__ emb,
            const float* __restrict__ Wih_f, const float* __restrict__ Whh_f,
            const float* __restrict__ bih_f, const float* __restrict__ bhh_f,
            const float* __restrict__ Wih_b, const float* __restrict__ Whh_b,
            const float* __restrict__ bih_b, const float* __restrict__ bhh_b,
            unsigned short* __restrict__ h_ex, unsigned* __restrict__ cnt,
            unsigned short* __restrict__ h_all)
{
  __shared__ __align__(16) unsigned short WihLds[64*256];   // 32 KB
  __shared__ __align__(16) unsigned short tile[32][16];     // 1 KB transpose tile

  const int bid  = blockIdx.x;
  const int dir  = bid & 1;
  const int w    = bid >> 1;          // 0..15
  const int tid  = threadIdx.x;
  const int wave = tid >> 6;          // Mtile (batch half)
  const int lane = tid & 63;
  const int l15  = lane & 15;
  const int lq   = lane >> 4;

  const float* Wih = dir ? Wih_b : Wih_f;
  const float* Whh = dir ? Whh_b : Whh_f;
  const float* bih = dir ? bih_b : bih_f;
  const float* bhh = dir ? bhh_b : bhh_f;

  // stage Wih slice -> LDS bf16, XOR-swizzled
  for (int idx = tid; idx < 64*256; idx += 128){
    int n = idx >> 8, kus = idx & 255;
    int j = (n >> 4)*256 + w*16 + (n & 15);    // gate*256 + unit
    WihLds[n*256 + (kus ^ ((n & 7) << 3))] = (unsigned short)f2bf(Wih[j*256 + kus]);
  }

  // Whh fragments in registers: B[k][col] = Whh[row=g*256+16w+l15][k]
  short8 wh[4][8];
  #pragma unroll
  for (int g = 0; g < 4; ++g){
    int j = g*256 + w*16 + l15;
    #pragma unroll
    for (int kc = 0; kc < 8; ++kc){
      const float* p = Whh + j*256 + kc*32 + lq*8;
      float4 a = *(const float4*)p, b = *(const float4*)(p + 4);
      wh[g][kc] = pack8v(a, b);
    }
  }
  float bias[4];
  #pragma unroll
  for (int g = 0; g < 4; ++g){
    int j = g*256 + w*16 + l15;
    bias[g] = bih[j] + bhh[j];
  }

  float c[4] = {0.f, 0.f, 0.f, 0.f};
  unsigned* cnt_d = cnt + dir*T_;
  const int arow = wave*16 + l15;                 // A-fragment row (batch)
  int tok = sent[arow*T_ + (dir ? (T_-1) : 0)];   // prefetched token

  __syncthreads();

  for (int s = 0; s < T_; ++s){
    const int t_idx = dir ? (T_-1 - s) : s;

    // ---- x part: loads + pack + 32 MFMAs, all independent of the barrier ----
    const float* xr = emb + (long)tok*E_ + lq*8;
    float4 xa0[8], xa1[8];
    #pragma unroll
    for (int kc = 0; kc < 8; ++kc){
      xa0[kc] = *(const float4*)(xr + kc*32);
      xa1[kc] = *(const float4*)(xr + kc*32 + 4);
    }
    if (s + 1 < T_) tok = sent[arow*T_ + (dir ? (T_-2 - s) : (s+1))];

    f32x4 acc[4];
    #pragma unroll
    for (int g = 0; g < 4; ++g) acc[g] = (f32x4){bias[g], bias[g], bias[g], bias[g]};

    #pragma unroll
    for (int kc = 0; kc < 8; ++kc){
      short8 xa = pack8v(xa0[kc], xa1[kc]);
      #pragma unroll
      for (int g = 0; g < 4; ++g){
        int n = g*16 + l15;
        short8 bw = *(const short8*)&WihLds[n*256 + ((kc*32 + lq*8) ^ ((n & 7) << 3))];
        acc[g] = __builtin_amdgcn_mfma_f32_16x16x32_bf16(xa, bw, acc[g], 0, 0, 0);
      }
    }

    // ---- wait for h(s) from all 16 wgs of this direction (no fences!) ----
    if (s > 0){
      if (tid == 0){
        while (__hip_atomic_load(&cnt_d[s-1], __ATOMIC_RELAXED,
                                 __HIP_MEMORY_SCOPE_AGENT) < NWGD) { }
      }
      __syncthreads();
    }

    // ---- h fragments via agent-scope 8B atomic loads (bypass stale L2) ----
    u64* hb64 = (u64*)h_ex + (size_t)(((s & 1)*2 + dir)*B_ + arow)*(HD_/4) + lq*2;
    short8 ha[8];
    #pragma unroll
    for (int kc = 0; kc < 8; ++kc){
      union { u64 q[2]; short8 v; } uq;
      uq.q[0] = __hip_atomic_load(hb64 + kc*8 + 0, __ATOMIC_RELAXED, __HIP_MEMORY_SCOPE_AGENT);
      uq.q[1] = __hip_atomic_load(hb64 + kc*8 + 1, __ATOMIC_RELAXED, __HIP_MEMORY_SCOPE_AGENT);
      ha[kc] = uq.v;
    }

    #pragma unroll
    for (int kc = 0; kc < 8; ++kc){
      #pragma unroll
      for (int g = 0; g < 4; ++g)
        acc[g] = __builtin_amdgcn_mfma_f32_16x16x32_bf16(ha[kc], wh[g][kc], acc[g], 0, 0, 0);
    }

    // ---- lane-local cell update -> LDS transpose tile ----
    #pragma unroll
    for (int r = 0; r < 4; ++r){
      float iv = sigm(acc[0][r]);
      float fv = sigm(acc[1][r]);
      float gv = tanh_f(acc[2][r]);
      float ov = sigm(acc[3][r]);
      c[r] = fv*c[r] + iv*gv;
      float hv = ov*tanh_f(c[r]);
      tile[wave*16 + lq*4 + r][l15] = (unsigned short)f2bf(hv);
    }
    // wave-local readback (each wave reads only rows it wrote -> no barrier)
    {
      int m2 = wave*16 + (lane >> 2);
      int u0 = (lane & 3)*4;
      u64 v = *(const u64*)&tile[m2][u0];
      size_t eoff = (size_t)m2*HD_ + w*16 + u0;     // elem offset, 8B-aligned
      u64* hw64 = (u64*)h_ex + (size_t)(((s+1) & 1)*2 + dir)*B_*(HD_/4) + eoff/4;
      __hip_atomic_store(hw64, v, __ATOMIC_RELAXED, __HIP_MEMORY_SCOPE_AGENT);
      u64* hs64 = (u64*)h_all + (size_t)(dir*T_ + t_idx)*B_*(HD_/4) + eoff/4;
      *hs64 = v;                                     // plain (consumed next kernel)
    }

    // __syncthreads drains vmcnt(0) per wave before the barrier -> all sc
    // stores are globally visible before tid 0 publishes the counter.
    __syncthreads();
    if (tid == 0)
      __hip_atomic_fetch_add(&cnt_d[s], 1u, __ATOMIC_RELAXED, __HIP_MEMORY_SCOPE_AGENT);
  }
}

// ---------------------------------------------------------------------------
// feats[b][t][k] = b_out[k] + [hf|hb] @ W_out^T   (K=512, N=48, M=B*T)
// ---------------------------------------------------------------------------
__global__ __launch_bounds__(128)
void feats_k(const unsigned short* __restrict__ h_all,
             const float* __restrict__ W_out, const float* __restrict__ b_out,
             float* __restrict__ feats)
{
  __shared__ __align__(16) unsigned short Wlds[48*512];   // 48 KB

  const int t0   = blockIdx.x * 4;
  const int tid  = threadIdx.x;
  const int wv   = tid >> 6;
  const int lane = tid & 63;
  const int l15  = lane & 15;
  const int lq   = lane >> 4;

  for (int idx = tid; idx < 48*512; idx += 128){
    int n = idx >> 9, kus = idx & 511;
    Wlds[n*512 + (kus ^ ((n & 7) << 3))] = (unsigned short)f2bf(W_out[n*512 + kus]);
  }
  float bo[3];
  #pragma unroll
  for (int nt = 0; nt < 3; ++nt) bo[nt] = b_out[nt*16 + l15];
  __syncthreads();

  #pragma unroll
  for (int mi = 0; mi < 4; ++mi){
    int mt = wv*4 + mi;
    int m  = mt*16 + l15;          // A row
    int b  = m & 31, tl = m >> 5;
    const unsigned short* hf = h_all + (size_t)((t0 + tl)*B_ + b)*HD_ + lq*8;
    const unsigned short* hb = h_all + (size_t)((T_ + t0 + tl)*B_ + b)*HD_ + lq*8;
    short8 af[16];
    #pragma unroll
    for (int kc = 0; kc < 8; ++kc) af[kc]     = *(const short8*)(hf + kc*32);
    #pragma unroll
    for (int kc = 0; kc < 8; ++kc) af[kc + 8] = *(const short8*)(hb + kc*32);

    f32x4 acc[3];
    #pragma unroll
    for (int nt = 0; nt < 3; ++nt) acc[nt] = (f32x4){bo[nt], bo[nt], bo[nt], bo[nt]};
    #pragma unroll
    for (int kc = 0; kc < 16; ++kc){
      #pragma unroll
      for (int nt = 0; nt < 3; ++nt){
        int n = nt*16 + l15;
        short8 bw = *(const short8*)&Wlds[n*512 + ((kc*32 + lq*8) ^ ((n & 7) << 3))];
        acc[nt] = __builtin_amdgcn_mfma_f32_16x16x32_bf16(af[kc], bw, acc[nt], 0, 0, 0);
      }
    }
    #pragma unroll
    for (int nt = 0; nt < 3; ++nt){
      #pragma unroll
      for (int r = 0; r < 4; ++r){
        int mm = mt*16 + lq*4 + r;
        int bb = mm & 31, tt = t0 + (mm >> 5);
        feats[(size_t)(bb*T_ + tt)*K_ + nt*16 + l15] = acc[nt][r];
      }
    }
  }
}

// ---------------------------------------------------------------------------
// Viterbi: one block (one wave) per batch element.
// ---------------------------------------------------------------------------
__global__ __launch_bounds__(64)
void viterbi_k(const float* __restrict__ feats, const float* __restrict__ trans,
               float* __restrict__ out)
{
  __shared__ float trans_s[K_*K_];
  __shared__ unsigned char bp[T_][K_];
  __shared__ unsigned char tags[T_];
  __shared__ float red[64];

  const int b = blockIdx.x, lane = threadIdx.x;
  for (int i = lane; i < K_*K_; i += 64) trans_s[i] = trans[i];

  float trow[K_];
  if (lane < K_){
    #pragma unroll
    for (int j = 0; j < K_; ++j) trow[j] = trans[lane*K_ + j];
  }
  float fv = (lane == K_-1) ? 0.0f : NEG_;
  const float* fb = feats + (size_t)b*T_*K_;
  __syncthreads();

  for (int t = 0; t < T_; ++t){
    float ft = (lane < K_) ? fb[t*K_ + lane] : 0.0f;
    float m = __shfl(fv, 0) + trow[0];
    int idx = 0;
    #pragma unroll
    for (int j = 1; j < K_; ++j){
      float v = __shfl(fv, j) + trow[j];
      if (v > m){ m = v; idx = j; }         // strict > == first-index argmax
    }
    if (lane < K_){
      fv = m + ft;
      bp[t][lane] = (unsigned char)idx;
    }
  }
  __syncthreads();

  red[lane] = fv;
  __syncthreads();
  int last = 0;
  {
    float bm = red[0];
    for (int k = 1; k < K_; ++k){ float v = red[k]; if (v > bm){ bm = v; last = k; } }
  }
  if (lane == 0){
    int tg = last;
    tags[T_-1] = (unsigned char)tg;
    for (int t = T_-1; t >= 1; --t){
      tg = bp[t][tg];
      tags[t-1] = (unsigned char)tg;
    }
  }
  __syncthreads();

  float sc = 0.0f;
  for (int t = 1 + lane; t < T_; t += 64){
    int tt = tags[t], tp = tags[t-1];
    sc += fb[t*K_ + tt] + trans_s[tp*K_ + tt];
  }
  if (lane == 0) sc += fb[(T_-1)*K_ + tags[0]];
  red[lane] = sc;
  __syncthreads();
  if (lane == 0){
    float tot = 0.f;
    for (int i = 0; i < 64; ++i) tot += red[i];
    out[b] = tot;
  }
  for (int t = lane; t < T_; t += 64)
    out[B_ + b*T_ + t] = (float)tags[t];
}

// ---------------------------------------------------------------------------
extern "C" void kernel_launch(void* const* d_in, const int* in_sizes, int n_in,
                              void* d_out, int out_size, void* d_ws, size_t ws_size,
                              hipStream_t stream)
{
  const int*   sent  = (const int*)  d_in[0];
  const float* emb   = (const float*)d_in[1];
  const float* Wih_f = (const float*)d_in[2];
  const float* Whh_f = (const float*)d_in[3];
  const float* bih_f = (const float*)d_in[4];
  const float* bhh_f = (const float*)d_in[5];
  const float* Wih_b = (const float*)d_in[6];
  const float* Whh_b = (const float*)d_in[7];
  const float* bih_b = (const float*)d_in[8];
  const float* bhh_b = (const float*)d_in[9];
  const float* W_out = (const float*)d_in[10];
  const float* b_out = (const float*)d_in[11];
  const float* trans = (const float*)d_in[12];

  char* ws = (char*)d_ws;
  // [0,65536)          h_ex  bf16 [2 buf][2 dir][32][256]
  // [65536,73728)      cnt   u32  [2 dir][1024]
  // [73728,+32MB)      h_all bf16 [2 dir][1024][32][256]
  // [..., +6MB)        feats f32  [32][1024][48]
  unsigned short* h_ex  = (unsigned short*)ws;
  unsigned*       cnt   = (unsigned*)(ws + 65536);
  unsigned short* h_all = (unsigned short*)(ws + 73728);
  float*          feats = (float*)(ws + 73728 + 33554432);

  hipMemsetAsync(ws, 0, 73728, stream);   // zero h-state + barrier counters

  hipLaunchKernelGGL(lstm_k, dim3(32), dim3(128), 0, stream,
                     sent, emb, Wih_f, Whh_f, bih_f, bhh_f,
                     Wih_b, Whh_b, bih_b, bhh_b, h_ex, cnt, h_all);
  hipLaunchKernelGGL(feats_k, dim3(256), dim3(128), 0, stream,
                     h_all, W_out, b_out, feats);
  hipLaunchKernelGGL(viterbi_k, dim3(32), dim3(64), 0, stream,
                     feats, trans, (float*)d_out);
}

// Round 5
// 4556.017 us; speedup vs baseline: 1.5365x; 1.2718x over previous
//
#include <hip/hip_runtime.h>
#include <hip/hip_bf16.h>
#include <stdint.h>

typedef __attribute__((ext_vector_type(4))) float f32x4;
typedef __attribute__((ext_vector_type(4))) int   i32x4;
typedef __attribute__((ext_vector_type(8))) short short8;
typedef unsigned long long u64;

#define B_   32
#define T_   1024
#define E_   256
#define HD_  256
#define K_   48
#define NEG_ (-10000.0f)
#define SMAX 1056   // flag step slots (>= T_+1)

__device__ __forceinline__ short f2bf(float f){
  union { float f; unsigned u; } v; v.f = f;
  unsigned r = v.u + 0x7fffu + ((v.u >> 16) & 1u);   // RNE
  return (short)(r >> 16);
}
__device__ __forceinline__ short8 pack8v(float4 a, float4 b){
  short8 r;
  r[0]=f2bf(a.x); r[1]=f2bf(a.y); r[2]=f2bf(a.z); r[3]=f2bf(a.w);
  r[4]=f2bf(b.x); r[5]=f2bf(b.y); r[6]=f2bf(b.z); r[7]=f2bf(b.w);
  return r;
}
__device__ __forceinline__ float sigm(float x){ return 1.0f/(1.0f + __expf(-x)); }
__device__ __forceinline__ float tanh_f(float x){ return 1.0f - 2.0f/(1.0f + __expf(2.0f*x)); }

// ---------------------------------------------------------------------------
// LSTM: 32 blocks = 16 per direction. Block (dir,w) owns hidden units
// [16w,16w+16). Barrier-free inner loop: per-(dir,step,wave,block) flag words
// (16B stride) signal "h slice stored at coherent point"; consumer waves poll
// their own wave's 16 flags and read h via sc0/sc1 dwordx4 loads.
// Release order: h stores (agent atomics) -> s_waitcnt vmcnt(0) -> flag store.
// Skew safety: flag[s+1][w] is set only after block w consumed h(s), so the
// 2-slot ping-pong cannot be overwritten while still being read.
// ---------------------------------------------------------------------------
__global__ __launch_bounds__(128, 1)
void lstm_k(const int* __restrict__ sent, const float* __restrict__ emb,
            const float* __restrict__ Wih_f, const float* __restrict__ Whh_f,
            const float* __restrict__ bih_f, const float* __restrict__ bhh_f,
            const float* __restrict__ Wih_b, const float* __restrict__ Whh_b,
            const float* __restrict__ bih_b, const float* __restrict__ bhh_b,
            unsigned short* __restrict__ h_ex, unsigned* __restrict__ flags,
            unsigned short* __restrict__ h_all)
{
  __shared__ __align__(16) unsigned short WihLds[64*256];   // 32 KB
  __shared__ __align__(16) unsigned short tile[32][16];     // 1 KB transpose tile

  const int bid  = blockIdx.x;
  const int dir  = bid & 1;
  const int w    = bid >> 1;          // 0..15 unit-slice id
  const int tid  = threadIdx.x;
  const int wave = tid >> 6;          // batch half
  const int lane = tid & 63;
  const int l15  = lane & 15;
  const int lq   = lane >> 4;

  const float* Wih = dir ? Wih_b : Wih_f;
  const float* Whh = dir ? Whh_b : Whh_f;
  const float* bih = dir ? bih_b : bih_f;
  const float* bhh = dir ? bhh_b : bhh_f;

  // stage Wih slice -> LDS bf16, XOR-swizzled
  for (int idx = tid; idx < 64*256; idx += 128){
    int n = idx >> 8, kus = idx & 255;
    int j = (n >> 4)*256 + w*16 + (n & 15);    // gate*256 + unit
    WihLds[n*256 + (kus ^ ((n & 7) << 3))] = (unsigned short)f2bf(Wih[j*256 + kus]);
  }

  // Whh fragments in registers: B[k][col] = Whh[row=g*256+16w+l15][k]
  short8 wh[4][8];
  #pragma unroll
  for (int g = 0; g < 4; ++g){
    int j = g*256 + w*16 + l15;
    #pragma unroll
    for (int kc = 0; kc < 8; ++kc){
      const float* p = Whh + j*256 + kc*32 + lq*8;
      float4 a = *(const float4*)p, b = *(const float4*)(p + 4);
      wh[g][kc] = pack8v(a, b);
    }
  }
  float bias[4];
  #pragma unroll
  for (int g = 0; g < 4; ++g){
    int j = g*256 + w*16 + l15;
    bias[g] = bih[j] + bhh[j];
  }

  float c[4] = {0.f, 0.f, 0.f, 0.f};
  const int arow = wave*16 + l15;                 // A-fragment row (batch)
  int tok = sent[arow*T_ + (dir ? (T_-1) : 0)];   // prefetched token

  __syncthreads();   // the only block barrier: WihLds staged

  for (int s = 0; s < T_; ++s){
    const int t_idx = dir ? (T_-1 - s) : s;

    // ---- x part: loads + pack + 32 MFMAs (off the critical sync path) ----
    const float* xr = emb + (long)tok*E_ + lq*8;
    float4 xa0[8], xa1[8];
    #pragma unroll
    for (int kc = 0; kc < 8; ++kc){
      xa0[kc] = *(const float4*)(xr + kc*32);
      xa1[kc] = *(const float4*)(xr + kc*32 + 4);
    }
    if (s + 1 < T_) tok = sent[arow*T_ + (dir ? (T_-2 - s) : (s+1))];

    f32x4 acc[4];
    #pragma unroll
    for (int g = 0; g < 4; ++g) acc[g] = (f32x4){bias[g], bias[g], bias[g], bias[g]};

    #pragma unroll
    for (int kc = 0; kc < 8; ++kc){
      short8 xa = pack8v(xa0[kc], xa1[kc]);
      #pragma unroll
      for (int g = 0; g < 4; ++g){
        int n = g*16 + l15;
        short8 bw = *(const short8*)&WihLds[n*256 + ((kc*32 + lq*8) ^ ((n & 7) << 3))];
        acc[g] = __builtin_amdgcn_mfma_f32_16x16x32_bf16(xa, bw, acc[g], 0, 0, 0);
      }
    }

    if (s > 0){
      // ---- poll this wave's 16 flags (lane j polls flag of block j&15) ----
      const unsigned* fl = flags +
          ((((size_t)dir*SMAX + s)*2 + wave)*16 + l15)*4;   // 16B stride
      for (;;){
        unsigned v = __hip_atomic_load(fl, __ATOMIC_RELAXED, __HIP_MEMORY_SCOPE_AGENT);
        if (__all(v != 0)) break;
      }

      // ---- h fragments: 8 coherent 16B loads (bypass stale L2) ----
      const unsigned short* hb = h_ex + ((size_t)(s & 1)*2 + dir)*B_*HD_
                                 + (size_t)arow*HD_ + lq*8;
      i32x4 hv[8];
      #pragma unroll
      for (int kc = 0; kc < 8; ++kc)
        asm volatile("global_load_dwordx4 %0, %1, off sc0 sc1"
                     : "=v"(hv[kc]) : "v"(hb + kc*32));
      asm volatile("s_waitcnt vmcnt(0)" ::: "memory");
      __builtin_amdgcn_sched_barrier(0);

      #pragma unroll
      for (int kc = 0; kc < 8; ++kc){
        short8 ha = __builtin_bit_cast(short8, hv[kc]);
        #pragma unroll
        for (int g = 0; g < 4; ++g)
          acc[g] = __builtin_amdgcn_mfma_f32_16x16x32_bf16(ha, wh[g][kc], acc[g], 0, 0, 0);
      }
    }

    // ---- lane-local cell update -> LDS transpose tile (wave-local) ----
    #pragma unroll
    for (int r = 0; r < 4; ++r){
      float iv = sigm(acc[0][r]);
      float fv = sigm(acc[1][r]);
      float gv = tanh_f(acc[2][r]);
      float ov = sigm(acc[3][r]);
      c[r] = fv*c[r] + iv*gv;
      float hv = ov*tanh_f(c[r]);
      tile[wave*16 + lq*4 + r][l15] = (unsigned short)f2bf(hv);
    }
    // coalesced readback (each wave reads only rows it wrote)
    {
      int m2 = wave*16 + (lane >> 2);
      int u0 = (lane & 3)*4;
      u64 v = *(const u64*)&tile[m2][u0];
      size_t eoff = (size_t)m2*HD_ + w*16 + u0;     // elem offset, 8B-aligned
      u64* hw64 = (u64*)h_ex + ((size_t)((s+1) & 1)*2 + dir)*B_*(HD_/4) + eoff/4;
      __hip_atomic_store(hw64, v, __ATOMIC_RELAXED, __HIP_MEMORY_SCOPE_AGENT);
      u64* hs64 = (u64*)h_all + ((size_t)dir*T_ + t_idx)*B_*(HD_/4) + eoff/4;
      *hs64 = v;                                     // plain (consumed next kernel)
    }

    // ---- release: wait own stores acked, then publish this wave's flag ----
    asm volatile("s_waitcnt vmcnt(0)" ::: "memory");
    if (lane == 0)
      __hip_atomic_store(flags + ((((size_t)dir*SMAX + (s+1))*2 + wave)*16 + w)*4,
                         1u, __ATOMIC_RELAXED, __HIP_MEMORY_SCOPE_AGENT);
  }
}

// ---------------------------------------------------------------------------
// feats[b][t][k] = b_out[k] + [hf|hb] @ W_out^T   (K=512, N=48, M=B*T)
// ---------------------------------------------------------------------------
__global__ __launch_bounds__(128)
void feats_k(const unsigned short* __restrict__ h_all,
             const float* __restrict__ W_out, const float* __restrict__ b_out,
             float* __restrict__ feats)
{
  __shared__ __align__(16) unsigned short Wlds[48*512];   // 48 KB

  const int t0   = blockIdx.x * 4;
  const int tid  = threadIdx.x;
  const int wv   = tid >> 6;
  const int lane = tid & 63;
  const int l15  = lane & 15;
  const int lq   = lane >> 4;

  for (int idx = tid; idx < 48*512; idx += 128){
    int n = idx >> 9, kus = idx & 511;
    Wlds[n*512 + (kus ^ ((n & 7) << 3))] = (unsigned short)f2bf(W_out[n*512 + kus]);
  }
  float bo[3];
  #pragma unroll
  for (int nt = 0; nt < 3; ++nt) bo[nt] = b_out[nt*16 + l15];
  __syncthreads();

  #pragma unroll
  for (int mi = 0; mi < 4; ++mi){
    int mt = wv*4 + mi;
    int m  = mt*16 + l15;          // A row
    int b  = m & 31, tl = m >> 5;
    const unsigned short* hf = h_all + (size_t)((t0 + tl)*B_ + b)*HD_ + lq*8;
    const unsigned short* hb = h_all + (size_t)((T_ + t0 + tl)*B_ + b)*HD_ + lq*8;
    short8 af[16];
    #pragma unroll
    for (int kc = 0; kc < 8; ++kc) af[kc]     = *(const short8*)(hf + kc*32);
    #pragma unroll
    for (int kc = 0; kc < 8; ++kc) af[kc + 8] = *(const short8*)(hb + kc*32);

    f32x4 acc[3];
    #pragma unroll
    for (int nt = 0; nt < 3; ++nt) acc[nt] = (f32x4){bo[nt], bo[nt], bo[nt], bo[nt]};
    #pragma unroll
    for (int kc = 0; kc < 16; ++kc){
      #pragma unroll
      for (int nt = 0; nt < 3; ++nt){
        int n = nt*16 + l15;
        short8 bw = *(const short8*)&Wlds[n*512 + ((kc*32 + lq*8) ^ ((n & 7) << 3))];
        acc[nt] = __builtin_amdgcn_mfma_f32_16x16x32_bf16(af[kc], bw, acc[nt], 0, 0, 0);
      }
    }
    #pragma unroll
    for (int nt = 0; nt < 3; ++nt){
      #pragma unroll
      for (int r = 0; r < 4; ++r){
        int mm = mt*16 + lq*4 + r;
        int bb = mm & 31, tt = t0 + (mm >> 5);
        feats[(size_t)(bb*T_ + tt)*K_ + nt*16 + l15] = acc[nt][r];
      }
    }
  }
}

// ---------------------------------------------------------------------------
// Viterbi: one block (one wave) per batch element.
// ---------------------------------------------------------------------------
__global__ __launch_bounds__(64)
void viterbi_k(const float* __restrict__ feats, const float* __restrict__ trans,
               float* __restrict__ out)
{
  __shared__ float trans_s[K_*K_];
  __shared__ unsigned char bp[T_][K_];
  __shared__ unsigned char tags[T_];
  __shared__ float red[64];

  const int b = blockIdx.x, lane = threadIdx.x;
  for (int i = lane; i < K_*K_; i += 64) trans_s[i] = trans[i];

  float trow[K_];
  if (lane < K_){
    #pragma unroll
    for (int j = 0; j < K_; ++j) trow[j] = trans[lane*K_ + j];
  }
  float fv = (lane == K_-1) ? 0.0f : NEG_;
  const float* fb = feats + (size_t)b*T_*K_;
  __syncthreads();

  for (int t = 0; t < T_; ++t){
    float ft = (lane < K_) ? fb[t*K_ + lane] : 0.0f;
    float m = __shfl(fv, 0) + trow[0];
    int idx = 0;
    #pragma unroll
    for (int j = 1; j < K_; ++j){
      float v = __shfl(fv, j) + trow[j];
      if (v > m){ m = v; idx = j; }         // strict > == first-index argmax
    }
    if (lane < K_){
      fv = m + ft;
      bp[t][lane] = (unsigned char)idx;
    }
  }
  __syncthreads();

  red[lane] = fv;
  __syncthreads();
  int last = 0;
  {
    float bm = red[0];
    for (int k = 1; k < K_; ++k){ float v = red[k]; if (v > bm){ bm = v; last = k; } }
  }
  if (lane == 0){
    int tg = last;
    tags[T_-1] = (unsigned char)tg;
    for (int t = T_-1; t >= 1; --t){
      tg = bp[t][tg];
      tags[t-1] = (unsigned char)tg;
    }
  }
  __syncthreads();

  float sc = 0.0f;
  for (int t = 1 + lane; t < T_; t += 64){
    int tt = tags[t], tp = tags[t-1];
    sc += fb[t*K_ + tt] + trans_s[tp*K_ + tt];
  }
  if (lane == 0) sc += fb[(T_-1)*K_ + tags[0]];
  red[lane] = sc;
  __syncthreads();
  if (lane == 0){
    float tot = 0.f;
    for (int i = 0; i < 64; ++i) tot += red[i];
    out[b] = tot;
  }
  for (int t = lane; t < T_; t += 64)
    out[B_ + b*T_ + t] = (float)tags[t];
}

// ---------------------------------------------------------------------------
extern "C" void kernel_launch(void* const* d_in, const int* in_sizes, int n_in,
                              void* d_out, int out_size, void* d_ws, size_t ws_size,
                              hipStream_t stream)
{
  const int*   sent  = (const int*)  d_in[0];
  const float* emb   = (const float*)d_in[1];
  const float* Wih_f = (const float*)d_in[2];
  const float* Whh_f = (const float*)d_in[3];
  const float* bih_f = (const float*)d_in[4];
  const float* bhh_f = (const float*)d_in[5];
  const float* Wih_b = (const float*)d_in[6];
  const float* Whh_b = (const float*)d_in[7];
  const float* bih_b = (const float*)d_in[8];
  const float* bhh_b = (const float*)d_in[9];
  const float* W_out = (const float*)d_in[10];
  const float* b_out = (const float*)d_in[11];
  const float* trans = (const float*)d_in[12];

  char* ws = (char*)d_ws;
  // [0, 64KB)            h_ex  bf16 [2 slot][2 dir][32][256]
  // [64KB, +2112KB)      flags u32, 16B stride: [2 dir][1056 s][2 wave][16 w]
  // [2228224, +32MB)     h_all bf16 [2 dir][1024][32][256]
  // [35782656, +6MB)     feats f32  [32][1024][48]
  unsigned short* h_ex  = (unsigned short*)ws;
  unsigned*       flags = (unsigned*)(ws + 65536);
  unsigned short* h_all = (unsigned short*)(ws + 2228224);
  float*          feats = (float*)(ws + 35782656);

  hipMemsetAsync(ws + 65536, 0, 2162688, stream);   // flags <- 0 (poison is 0xAA!)

  hipLaunchKernelGGL(lstm_k, dim3(32), dim3(128), 0, stream,
                     sent, emb, Wih_f, Whh_f, bih_f, bhh_f,
                     Wih_b, Whh_b, bih_b, bhh_b, h_ex, flags, h_all);
  hipLaunchKernelGGL(feats_k, dim3(256), dim3(128), 0, stream,
                     h_all, W_out, b_out, feats);
  hipLaunchKernelGGL(viterbi_k, dim3(32), dim3(64), 0, stream,
                     feats, trans, (float*)d_out);
}

// Round 9
// 3783.185 us; speedup vs baseline: 1.8504x; 1.2043x over previous
//
#include <hip/hip_runtime.h>
#include <hip/hip_bf16.h>
#include <stdint.h>

typedef __attribute__((ext_vector_type(4))) float f32x4;
typedef __attribute__((ext_vector_type(4))) int   i32x4;
typedef __attribute__((ext_vector_type(8))) short short8;
typedef unsigned long long u64;

#define B_   32
#define T_   1024
#define E_   256
#define HD_  256
#define K_   48
#define NEG_ (-10000.0f)

__device__ __forceinline__ short f2bf(float f){
  union { float f; unsigned u; } v; v.f = f;
  unsigned r = v.u + 0x7fffu + ((v.u >> 16) & 1u);   // RNE
  return (short)(r >> 16);
}
__device__ __forceinline__ short8 pack8v(float4 a, float4 b){
  short8 r;
  r[0]=f2bf(a.x); r[1]=f2bf(a.y); r[2]=f2bf(a.z); r[3]=f2bf(a.w);
  r[4]=f2bf(b.x); r[5]=f2bf(b.y); r[6]=f2bf(b.z); r[7]=f2bf(b.w);
  return r;
}
__device__ __forceinline__ float sigm(float x){ return 1.0f/(1.0f + __expf(-x)); }
__device__ __forceinline__ float tanh_f(float x){ return 1.0f - 2.0f/(1.0f + __expf(2.0f*x)); }

// ---------------------------------------------------------------------------
// x gather: x_bf16[t][b][e] = bf16(emb[sent[b][t]][e]).  Shared by both dirs.
// ---------------------------------------------------------------------------
__global__ __launch_bounds__(256)
void xgather_k(const int* __restrict__ sent, const float* __restrict__ emb,
               unsigned short* __restrict__ xbf)
{
  const int t = blockIdx.x;
  const int b = threadIdx.x >> 3;
  const int e0 = (threadIdx.x & 7) * 4;
  const int tok = sent[b*T_ + t];
  const float* src = emb + (size_t)tok*E_;
  unsigned short* dst = xbf + ((size_t)t*B_ + b)*E_;
  #pragma unroll
  for (int i = 0; i < 8; ++i){
    float4 v = *(const float4*)(src + e0 + i*32);
    union { unsigned short s[4]; u64 q; } u;
    u.s[0]=f2bf(v.x); u.s[1]=f2bf(v.y); u.s[2]=f2bf(v.z); u.s[3]=f2bf(v.w);
    *(u64*)(dst + e0 + i*32) = u.q;
  }
}

// ---------------------------------------------------------------------------
// LSTM: 32 blocks = 16 per direction; block (dir,w) owns units [16w,16w+16).
// Data-is-the-signal sync: h_all pre-filled with bf16 NaN (0xFFFF). Producers
// store h via 8B agent atomics; consumers poll the h fragments themselves
// (sc0/sc1 dwordx4) until no NaN sentinel remains -> detection returns the
// data. No flags, no producer ack, no block barrier in the loop.
// h_all is write-once per (dir,t) -> no WAR hazard anywhere.
// ---------------------------------------------------------------------------
__global__ __launch_bounds__(128, 1)
void lstm_k(const unsigned short* __restrict__ xbf,
            const float* __restrict__ Whh_f, const float* __restrict__ bih_f,
            const float* __restrict__ bhh_f, const float* __restrict__ Whh_b,
            const float* __restrict__ bih_b, const float* __restrict__ bhh_b,
            const float* __restrict__ Wih_f, const float* __restrict__ Wih_b,
            unsigned short* __restrict__ h_all)
{
  __shared__ __align__(16) unsigned short WihLds[64*256];   // 32 KB
  __shared__ __align__(16) unsigned short tile[32][16];     // 1 KB transpose tile

  const int bid  = blockIdx.x;
  const int dir  = bid & 1;
  const int w    = bid >> 1;          // 0..15 unit-slice id
  const int tid  = threadIdx.x;
  const int wave = tid >> 6;          // batch half
  const int lane = tid & 63;
  const int l15  = lane & 15;
  const int lq   = lane >> 4;

  const float* Wih = dir ? Wih_b : Wih_f;
  const float* Whh = dir ? Whh_b : Whh_f;
  const float* bih = dir ? bih_b : bih_f;
  const float* bhh = dir ? bhh_b : bhh_f;

  // stage Wih slice -> LDS bf16, XOR-swizzled
  for (int idx = tid; idx < 64*256; idx += 128){
    int n = idx >> 8, kus = idx & 255;
    int j = (n >> 4)*256 + w*16 + (n & 15);    // gate*256 + unit
    WihLds[n*256 + (kus ^ ((n & 7) << 3))] = (unsigned short)f2bf(Wih[j*256 + kus]);
  }

  // Whh fragments in registers: B[k][col] = Whh[row=g*256+16w+l15][k]
  short8 wh[4][8];
  #pragma unroll
  for (int g = 0; g < 4; ++g){
    int j = g*256 + w*16 + l15;
    #pragma unroll
    for (int kc = 0; kc < 8; ++kc){
      const float* p = Whh + j*256 + kc*32 + lq*8;
      float4 a = *(const float4*)p, b = *(const float4*)(p + 4);
      wh[g][kc] = pack8v(a, b);
    }
  }
  float bias[4];
  #pragma unroll
  for (int g = 0; g < 4; ++g){
    int j = g*256 + w*16 + l15;
    bias[g] = bih[j] + bhh[j];
  }

  float c[4] = {0.f, 0.f, 0.f, 0.f};
  const int arow = wave*16 + l15;                 // A-fragment row (batch)

  __syncthreads();   // the only block barrier: WihLds staged

  for (int s = 0; s < T_; ++s){
    const int t_idx  = dir ? (T_-1 - s) : s;

    // ---- x part: 8 plain 16B bf16 loads + 32 MFMAs (pre-poll filler) ----
    const unsigned short* xr = xbf + ((size_t)t_idx*B_ + arow)*E_ + lq*8;
    short8 xa[8];
    #pragma unroll
    for (int kc = 0; kc < 8; ++kc) xa[kc] = *(const short8*)(xr + kc*32);

    f32x4 acc[4];
    #pragma unroll
    for (int g = 0; g < 4; ++g) acc[g] = (f32x4){bias[g], bias[g], bias[g], bias[g]};

    #pragma unroll
    for (int kc = 0; kc < 8; ++kc){
      #pragma unroll
      for (int g = 0; g < 4; ++g){
        int n = g*16 + l15;
        short8 bw = *(const short8*)&WihLds[n*256 + ((kc*32 + lq*8) ^ ((n & 7) << 3))];
        acc[g] = __builtin_amdgcn_mfma_f32_16x16x32_bf16(xa[kc], bw, acc[g], 0, 0, 0);
      }
    }

    if (s > 0){
      // ---- poll the h(s-1) data itself: detect == data arrival ----
      const int t_prev = dir ? (T_ - s) : (s - 1);
      const unsigned short* hb = h_all + ((size_t)dir*T_ + t_prev)*B_*HD_
                                 + (size_t)arow*HD_ + lq*8;
      i32x4 hv[8];
      for (;;){
        #pragma unroll
        for (int kc = 0; kc < 8; ++kc)
          asm volatile("global_load_dwordx4 %0, %1, off sc0 sc1"
                       : "=&v"(hv[kc]) : "v"(hb + kc*32));
        asm volatile("s_waitcnt vmcnt(0)" ::: "memory");
        __builtin_amdgcn_sched_barrier(0);
        int bad = 0;
        #pragma unroll
        for (int kc = 0; kc < 8; ++kc)
          bad |= (hv[kc][0] == -1) | (hv[kc][2] == -1);   // NaN sentinel per 8B store
        if (!__any(bad)) break;
      }

      #pragma unroll
      for (int kc = 0; kc < 8; ++kc){
        short8 ha = __builtin_bit_cast(short8, hv[kc]);
        #pragma unroll
        for (int g = 0; g < 4; ++g)
          acc[g] = __builtin_amdgcn_mfma_f32_16x16x32_bf16(ha, wh[g][kc], acc[g], 0, 0, 0);
      }
    }

    // ---- lane-local cell update -> LDS transpose tile (wave-local) ----
    #pragma unroll
    for (int r = 0; r < 4; ++r){
      float iv = sigm(acc[0][r]);
      float fv = sigm(acc[1][r]);
      float gv = tanh_f(acc[2][r]);
      float ov = sigm(acc[3][r]);
      c[r] = fv*c[r] + iv*gv;
      float hv = ov*tanh_f(c[r]);
      tile[wave*16 + lq*4 + r][l15] = (unsigned short)f2bf(hv);
    }
    // coalesced readback (each wave reads only rows it wrote) + single store
    {
      int m2 = wave*16 + (lane >> 2);
      int u0 = (lane & 3)*4;
      u64 v = *(const u64*)&tile[m2][u0];
      size_t eoff = (size_t)m2*HD_ + w*16 + u0;     // elem offset, 8B-aligned
      u64* hs64 = (u64*)h_all + ((size_t)dir*T_ + t_idx)*B_*(HD_/4) + eoff/4;
      __hip_atomic_store(hs64, v, __ATOMIC_RELAXED, __HIP_MEMORY_SCOPE_AGENT);
    }
    // no release needed: the stores ARE the signal; next poll's vmcnt(0)
    // retires them in the shadow of its own load latency.
  }
}

// ---------------------------------------------------------------------------
// feats[b][t][k] = b_out[k] + [hf|hb] @ W_out^T   (K=512, N=48, M=B*T)
// ---------------------------------------------------------------------------
__global__ __launch_bounds__(128)
void feats_k(const unsigned short* __restrict__ h_all,
             const float* __restrict__ W_out, const float* __restrict__ b_out,
             float* __restrict__ feats)
{
  __shared__ __align__(16) unsigned short Wlds[48*512];   // 48 KB

  const int t0   = blockIdx.x * 4;
  const int tid  = threadIdx.x;
  const int wv   = tid >> 6;
  const int lane = tid & 63;
  const int l15  = lane & 15;
  const int lq   = lane >> 4;

  for (int idx = tid; idx < 48*512; idx += 128){
    int n = idx >> 9, kus = idx & 511;
    Wlds[n*512 + (kus ^ ((n & 7) << 3))] = (unsigned short)f2bf(W_out[n*512 + kus]);
  }
  float bo[3];
  #pragma unroll
  for (int nt = 0; nt < 3; ++nt) bo[nt] = b_out[nt*16 + l15];
  __syncthreads();

  #pragma unroll
  for (int mi = 0; mi < 4; ++mi){
    int mt = wv*4 + mi;
    int m  = mt*16 + l15;          // A row
    int b  = m & 31, tl = m >> 5;
    const unsigned short* hf = h_all + (size_t)((t0 + tl)*B_ + b)*HD_ + lq*8;
    const unsigned short* hb = h_all + (size_t)((T_ + t0 + tl)*B_ + b)*HD_ + lq*8;
    short8 af[16];
    #pragma unroll
    for (int kc = 0; kc < 8; ++kc) af[kc]     = *(const short8*)(hf + kc*32);
    #pragma unroll
    for (int kc = 0; kc < 8; ++kc) af[kc + 8] = *(const short8*)(hb + kc*32);

    f32x4 acc[3];
    #pragma unroll
    for (int nt = 0; nt < 3; ++nt) acc[nt] = (f32x4){bo[nt], bo[nt], bo[nt], bo[nt]};
    #pragma unroll
    for (int kc = 0; kc < 16; ++kc){
      #pragma unroll
      for (int nt = 0; nt < 3; ++nt){
        int n = nt*16 + l15;
        short8 bw = *(const short8*)&Wlds[n*512 + ((kc*32 + lq*8) ^ ((n & 7) << 3))];
        acc[nt] = __builtin_amdgcn_mfma_f32_16x16x32_bf16(af[kc], bw, acc[nt], 0, 0, 0);
      }
    }
    #pragma unroll
    for (int nt = 0; nt < 3; ++nt){
      #pragma unroll
      for (int r = 0; r < 4; ++r){
        int mm = mt*16 + lq*4 + r;
        int bb = mm & 31, tt = t0 + (mm >> 5);
        feats[(size_t)(bb*T_ + tt)*K_ + nt*16 + l15] = acc[nt][r];
      }
    }
  }
}

// ---------------------------------------------------------------------------
// Viterbi: one block (one wave) per batch element; ft prefetched one step.
// ---------------------------------------------------------------------------
__global__ __launch_bounds__(64)
void viterbi_k(const float* __restrict__ feats, const float* __restrict__ trans,
               float* __restrict__ out)
{
  __shared__ float trans_s[K_*K_];
  __shared__ unsigned char bp[T_][K_];
  __shared__ unsigned char tags[T_];
  __shared__ float red[64];

  const int b = blockIdx.x, lane = threadIdx.x;
  for (int i = lane; i < K_*K_; i += 64) trans_s[i] = trans[i];

  float trow[K_];
  if (lane < K_){
    #pragma unroll
    for (int j = 0; j < K_; ++j) trow[j] = trans[lane*K_ + j];
  }
  float fv = (lane == K_-1) ? 0.0f : NEG_;
  const float* fb = feats + (size_t)b*T_*K_;
  __syncthreads();

  float ft = (lane < K_) ? fb[lane] : 0.0f;
  for (int t = 0; t < T_; ++t){
    float ftn = (lane < K_ && t+1 < T_) ? fb[(t+1)*K_ + lane] : 0.0f;
    float m = __shfl(fv, 0) + trow[0];
    int idx = 0;
    #pragma unroll
    for (int j = 1; j < K_; ++j){
      float v = __shfl(fv, j) + trow[j];
      if (v > m){ m = v; idx = j; }         // strict > == first-index argmax
    }
    if (lane < K_){
      fv = m + ft;
      bp[t][lane] = (unsigned char)idx;
    }
    ft = ftn;
  }
  __syncthreads();

  red[lane] = fv;
  __syncthreads();
  int last = 0;
  {
    float bm = red[0];
    for (int k = 1; k < K_; ++k){ float v = red[k]; if (v > bm){ bm = v; last = k; } }
  }
  if (lane == 0){
    int tg = last;
    tags[T_-1] = (unsigned char)tg;
    for (int t = T_-1; t >= 1; --t){
      tg = bp[t][tg];
      tags[t-1] = (unsigned char)tg;
    }
  }
  __syncthreads();

  float sc = 0.0f;
  for (int t = 1 + lane; t < T_; t += 64){
    int tt = tags[t], tp = tags[t-1];
    sc += fb[t*K_ + tt] + trans_s[tp*K_ + tt];
  }
  if (lane == 0) sc += fb[(T_-1)*K_ + tags[0]];
  red[lane] = sc;
  __syncthreads();
  if (lane == 0){
    float tot = 0.f;
    for (int i = 0; i < 64; ++i) tot += red[i];
    out[b] = tot;
  }
  for (int t = lane; t < T_; t += 64)
    out[B_ + b*T_ + t] = (float)tags[t];
}

// ---------------------------------------------------------------------------
extern "C" void kernel_launch(void* const* d_in, const int* in_sizes, int n_in,
                              void* d_out, int out_size, void* d_ws, size_t ws_size,
                              hipStream_t stream)
{
  const int*   sent  = (const int*)  d_in[0];
  const float* emb   = (const float*)d_in[1];
  const float* Wih_f = (const float*)d_in[2];
  const float* Whh_f = (const float*)d_in[3];
  const float* bih_f = (const float*)d_in[4];
  const float* bhh_f = (const float*)d_in[5];
  const float* Wih_b = (const float*)d_in[6];
  const float* Whh_b = (const float*)d_in[7];
  const float* bih_b = (const float*)d_in[8];
  const float* bhh_b = (const float*)d_in[9];
  const float* W_out = (const float*)d_in[10];
  const float* b_out = (const float*)d_in[11];
  const float* trans = (const float*)d_in[12];

  char* ws = (char*)d_ws;
  // [0, 32MB)        h_all bf16 [2 dir][1024 t][32 b][256 u]  (NaN-sentinel)
  // [32MB, +6MB)     feats f32  [32][1024][48]
  // [38MB, +16MB)    x_bf16     [1024 t][32 b][256 e]
  unsigned short* h_all = (unsigned short*)ws;
  float*          feats = (float*)(ws + 33554432);
  unsigned short* xbf   = (unsigned short*)(ws + 33554432 + 6291456);

  hipMemsetAsync(h_all, 0xFF, 33554432, stream);   // bf16 NaN sentinel

  hipLaunchKernelGGL(xgather_k, dim3(T_), dim3(256), 0, stream, sent, emb, xbf);
  hipLaunchKernelGGL(lstm_k, dim3(32), dim3(128), 0, stream,
                     xbf, Whh_f, bih_f, bhh_f, Whh_b, bih_b, bhh_b,
                     Wih_f, Wih_b, h_all);
  hipLaunchKernelGGL(feats_k, dim3(256), dim3(128), 0, stream,
                     h_all, W_out, b_out, feats);
  hipLaunchKernelGGL(viterbi_k, dim3(32), dim3(64), 0, stream,
                     feats, trans, (float*)d_out);
}